// Round 4
// baseline (79.071 us; speedup 1.0000x reference)
//
#include <hip/hip_runtime.h>
#include <hip/hip_bf16.h>

// Problem constants (fixed by the reference)
#define Bz 8
#define Cc 256
#define HWp 23104            // 152*152
#define QF  5776             // HWp/4 : floats per quarter-plane (23104 B LDS)
#define Kk 1024
#define BK (Bz*Kk)
#define MARGIN_F 10.0f
#define BIGF 1e30f

typedef __attribute__((ext_vector_type(8))) short bf16x8;  // 8 bf16 = 4 VGPRs
typedef __attribute__((ext_vector_type(4))) float f32x4;   // MFMA 16x16 accumulator

// ---------------------------------------------------------------------------
// Kernel 0: plane-gather.  The scattered gather (2M random 4B loads, 64B-line
// efficiency 6%, MSHR-latency-bound at ~2 TB/s) is replaced by a STREAM:
// each block loads one quarter of one (b,c) channel plane into LDS with
// coalesced float4 loads (total = 189 MB = exactly the input size), then
// gathers the ~256 in-range indices from LDS and writes RAW bf16 to
// emb[b*K+k][c] (scattered 2B stores into a 4 MB L2-resident buffer).
// Normalization is deferred: it commutes out of the Gram.
// 23 KB LDS -> 6 blocks/CU, deep streaming pipeline.
// ---------------------------------------------------------------------------
__global__ __launch_bounds__(256) void plane_gather(
    const float* __restrict__ x, const int* __restrict__ ind,
    __hip_bfloat16* __restrict__ embr)
{
    __shared__ float pl[QF];
    int c = blockIdx.x, q = blockIdx.y, b = blockIdx.z;
    const float* src = x + (size_t)(b * Cc + c) * HWp + q * QF;
    #pragma unroll
    for (int i = 0; i < 6; ++i) {                 // 1444 float4 / 256 thr
        int idx = i * 256 + threadIdx.x;
        if (idx < QF / 4)
            *(float4*)(pl + idx * 4) = ((const float4*)src)[idx];
    }
    __syncthreads();
    int lo = q * QF;
    const int* indb = ind + b * Kk;
    #pragma unroll
    for (int kk = 0; kk < 4; ++kk) {
        int k  = kk * 256 + threadIdx.x;
        unsigned off = (unsigned)(indb[k] - lo);
        if (off < QF) {
            embr[(size_t)(b * Kk + k) * Cc + c] = __float2bfloat16(pl[off]);
        }
    }
}

// ---------------------------------------------------------------------------
// Kernel 1: per-row sum of squares of the RAW bf16 embeddings (coalesced:
// each thread owns a 64-channel quarter of one row), then
//   scl[r] = 10 / max(sqrt(ssq),1e-12),  si[r] = scl^2*ssq  (= ||emb||^2)
// Also initializes neg_min (harness poisons ws once, never re-poisons).
// ---------------------------------------------------------------------------
__global__ __launch_bounds__(256) void rownorm(
    const __hip_bfloat16* __restrict__ embr, float* __restrict__ scl,
    float* __restrict__ si, unsigned* __restrict__ neg)
{
    int row = blockIdx.x * 64 + (threadIdx.x >> 2);   // 128 blocks x 64 rows
    int cq  = threadIdx.x & 3;
    const ushort* r = (const ushort*)embr + (size_t)row * Cc + cq * 64;
    float s = 0.f;
    #pragma unroll
    for (int i = 0; i < 8; ++i) {
        bf16x8 v = *(const bf16x8*)(r + i * 8);
        #pragma unroll
        for (int j = 0; j < 8; ++j) {
            float f = __uint_as_float(((unsigned)(ushort)v[j]) << 16);
            s += f * f;
        }
    }
    s += __shfl_xor(s, 1);
    s += __shfl_xor(s, 2);
    if (cq == 0) {
        float sc = 10.0f / fmaxf(sqrtf(s), 1e-12f);
        scl[row] = sc;
        si[row]  = sc * sc * s;
        neg[row] = __float_as_uint(BIGF);
    }
}

// ---------------------------------------------------------------------------
// Kernel 2: Gram via bf16 MFMA on the RAW embeddings + fused masked-min.
// Identical MFMA structure to the verified R2 kernel; the normalization
// scale is folded into the epilogue:  d2 = si_i + si_j - 2*scl_i*scl_j*Graw.
// Duplicate-index rows are bitwise-identical raw bf16 -> d2_dup ~ 1e-3,
// clamped >= 0 BEFORE the uint-bit atomicMin.
// ---------------------------------------------------------------------------
#define TILE 128
__global__ __launch_bounds__(256) void gram_mfma_min(
    const __hip_bfloat16* __restrict__ emb, const float* __restrict__ scl,
    const float* __restrict__ si, const int* __restrict__ mask,
    unsigned* __restrict__ neg)
{
    int b  = blockIdx.z;
    int i0 = blockIdx.y * TILE;
    int j0 = blockIdx.x * TILE;
    int w  = threadIdx.x >> 6, l = threadIdx.x & 63;
    int wr = w >> 1, wc = w & 1;          // wave's 64x64 quadrant
    int lr = l & 15, lg = l >> 4;         // lane row / k-group

    const short* E = (const short*)emb + (size_t)b * Kk * Cc;
    int arow = i0 + wr * 64 + lr;
    int brow = j0 + wc * 64 + lr;

    f32x4 acc[4][4] = {};
    for (int k0 = 0; k0 < Cc; k0 += 32) {
        bf16x8 af[4], bfr[4];
        #pragma unroll
        for (int f = 0; f < 4; ++f) {
            af[f]  = *(const bf16x8*)(E + (size_t)(arow + f*16) * Cc + k0 + lg*8);
            bfr[f] = *(const bf16x8*)(E + (size_t)(brow + f*16) * Cc + k0 + lg*8);
        }
        #pragma unroll
        for (int fi = 0; fi < 4; ++fi)
            #pragma unroll
            for (int fj = 0; fj < 4; ++fj)
                acc[fi][fj] = __builtin_amdgcn_mfma_f32_16x16x32_bf16(
                                  af[fi], bfr[fj], acc[fi][fj], 0, 0, 0);
    }

    const int* mb = mask + b * Kk;
    float sjv[4], cjv[4]; int jgv[4]; bool jva[4];
    #pragma unroll
    for (int fj = 0; fj < 4; ++fj) {
        int jg = j0 + wc*64 + fj*16 + lr;
        jgv[fj] = jg;
        sjv[fj] = si[b * Kk + jg];
        cjv[fj] = scl[b * Kk + jg];
        jva[fj] = (mb[jg] != 0);
    }
    #pragma unroll
    for (int fi = 0; fi < 4; ++fi) {
        #pragma unroll
        for (int r = 0; r < 4; ++r) {
            int ig = i0 + wr*64 + fi*16 + 4*lg + r;
            float siv = si[b * Kk + ig];
            float ci  = scl[b * Kk + ig];
            float m = BIGF;
            #pragma unroll
            for (int fj = 0; fj < 4; ++fj) {
                float d2 = fmaxf(siv + sjv[fj] - 2.0f * ci * cjv[fj] * acc[fi][fj][r], 0.0f);
                bool ok = jva[fj] && (jgv[fj] != ig);
                m = ok ? fminf(m, d2) : m;
            }
            #pragma unroll
            for (int off = 1; off < 16; off <<= 1)
                m = fminf(m, __shfl_xor(m, off));
            if (lr == 0)
                atomicMin(&neg[b * Kk + ig], __float_as_uint(m));
        }
    }
}

// ---------------------------------------------------------------------------
// Kernel 3: hinge = max(margin - sqrt(min_d2), 0) over valid anchors; mean.
// One 1024-thread block.
// ---------------------------------------------------------------------------
__global__ __launch_bounds__(1024) void hinge_final(
    const unsigned* __restrict__ neg, const int* __restrict__ mask,
    float* __restrict__ out)
{
    float h = 0.f, v = 0.f;
    for (int i = threadIdx.x; i < BK; i += 1024) {
        if (mask[i] != 0) {
            float d = sqrtf(__uint_as_float(neg[i]));
            h += fmaxf(MARGIN_F - d, 0.f);
            v += 1.f;
        }
    }
    #pragma unroll
    for (int off = 32; off; off >>= 1) {
        h += __shfl_xor(h, off);
        v += __shfl_xor(v, off);
    }
    __shared__ float sh[16], sv[16];
    int w = threadIdx.x >> 6;
    if ((threadIdx.x & 63) == 0) { sh[w] = h; sv[w] = v; }
    __syncthreads();
    if (threadIdx.x == 0) {
        float H = 0.f, V = 0.f;
        #pragma unroll
        for (int i = 0; i < 16; ++i) { H += sh[i]; V += sv[i]; }
        out[0] = H / V;
    }
}

// ---------------------------------------------------------------------------
extern "C" void kernel_launch(void* const* d_in, const int* in_sizes, int n_in,
                              void* d_out, int out_size, void* d_ws, size_t ws_size,
                              hipStream_t stream) {
    const float* x     = (const float*)d_in[0];   // [B,C,H,W] fp32
    const int*   ind   = (const int*)d_in[1];     // [B,K] int32
    const int*   mask  = (const int*)d_in[2];     // [B,K] int32
    float* out = (float*)d_out;

    // ws layout: embr bf16 [B*K][C] (4 MB) | scl f32 [B*K] | si f32 [B*K]
    //            | neg u32 [B*K]
    __hip_bfloat16* embr = (__hip_bfloat16*)d_ws;
    float*    scl = (float*)((char*)d_ws + (size_t)BK * Cc * sizeof(__hip_bfloat16));
    float*    si  = scl + BK;
    unsigned* neg = (unsigned*)(si + BK);

    dim3 g0(Cc, 4, Bz);                       // (channel, quarter, batch)
    plane_gather<<<g0, 256, 0, stream>>>(x, ind, embr);
    rownorm<<<BK / 64, 256, 0, stream>>>(embr, scl, si, neg);
    dim3 g2(Kk / TILE, Kk / TILE, Bz);
    gram_mfma_min<<<g2, 256, 0, stream>>>(embr, scl, si, mask, neg);
    hinge_final<<<1, 1024, 0, stream>>>(neg, mask, out);
}

// Round 5
// 72.831 us; speedup vs baseline: 1.0857x; 1.0857x over previous
//
#include <hip/hip_runtime.h>
#include <hip/hip_bf16.h>

// Problem constants (fixed by the reference)
#define Bz 8
#define Cc 256
#define HWp 23104            // 152*152 = 32 slices * 722
#define SL  722              // positions per slice
#define Kk 1024
#define BK (Bz*Kk)
#define MARGIN_F 10.0f
#define BIGF 1e30f

typedef __attribute__((ext_vector_type(8))) short bf16x8;  // 8 bf16 = 4 VGPRs
typedef __attribute__((ext_vector_type(4))) float f32x4;   // MFMA 16x16 accumulator

// ---------------------------------------------------------------------------
// Kernel 0: plane-gather, line-coalesced on BOTH sides.
// R3 lesson: 1-channel blocks made every 64B embr line shared by 32 blocks
// across non-coherent XCD L2s (partial-line RFO + ping-pong ~ 250MB hidden
// traffic).  Fix: block = 32 channels x 722-position slice.
//   reads : float2-coalesced stream, 32x722 floats/block (189 MB total)
//   LDS   : bf16 TRANSPOSED pl[pos][cpad=33] (bank stride 33 == conflict-free)
//   writes: per in-range k, ONE full 64B line embr[k][c0..c0+31] (4MB total,
//           each line written exactly once -- ind maps k to exactly one slice)
// ---------------------------------------------------------------------------
__global__ __launch_bounds__(256) void plane_gather(
    const float* __restrict__ x, const int* __restrict__ ind,
    __hip_bfloat16* __restrict__ embr)
{
    __shared__ ushort pl[SL * 33];                 // 47652 B -> 3 blocks/CU
    int s  = blockIdx.x;                           // slice 0..31
    int c0 = blockIdx.y * 32;                      // channel group
    int b  = blockIdx.z;
    int lane = threadIdx.x & 63, w = threadIdx.x >> 6;
    int lo = s * SL;

    // stream 32 rows (8 per wave), 361 float2 per row, convert->bf16->LDS^T
    #pragma unroll
    for (int i = 0; i < 8; ++i) {
        int cl = w * 8 + i;
        const float2* src = (const float2*)(x + (size_t)(b * Cc + c0 + cl) * HWp + lo);
        #pragma unroll
        for (int it = 0; it < 6; ++it) {
            int idx2 = it * 64 + lane;
            if (idx2 < SL / 2) {
                float2 v = src[idx2];
                pl[(idx2 * 2 + 0) * 33 + cl] = __hip_bfloat16_raw(__float2bfloat16(v.x)).x;
                pl[(idx2 * 2 + 1) * 33 + cl] = __hip_bfloat16_raw(__float2bfloat16(v.y)).x;
            }
        }
    }
    __syncthreads();

    // gather: thread t owns k = t, t+256, t+512, t+768 (~32 in-range/block)
    const int* indb = ind + b * Kk;
    #pragma unroll
    for (int kk = 0; kk < 4; ++kk) {
        int k = kk * 256 + threadIdx.x;
        unsigned off = (unsigned)(indb[k] - lo);
        if (off < (unsigned)SL) {
            const ushort* row = &pl[off * 33];
            uint dw[16];
            #pragma unroll
            for (int c2 = 0; c2 < 16; ++c2)
                dw[c2] = (uint)row[2 * c2] | ((uint)row[2 * c2 + 1] << 16);
            uint4* dst = (uint4*)((ushort*)embr + (size_t)(b * Kk + k) * Cc + c0);
            dst[0] = make_uint4(dw[0],  dw[1],  dw[2],  dw[3]);
            dst[1] = make_uint4(dw[4],  dw[5],  dw[6],  dw[7]);
            dst[2] = make_uint4(dw[8],  dw[9],  dw[10], dw[11]);
            dst[3] = make_uint4(dw[12], dw[13], dw[14], dw[15]);
        }
    }
}

// ---------------------------------------------------------------------------
// Kernel 1: per-row sum of squares of the RAW bf16 embeddings (coalesced),
//   scl[r] = 10 / max(sqrt(ssq),1e-12),  si[r] = scl^2*ssq
// Also initializes neg_min (harness poisons ws once, never re-poisons).
// ---------------------------------------------------------------------------
__global__ __launch_bounds__(256) void rownorm(
    const __hip_bfloat16* __restrict__ embr, float* __restrict__ scl,
    float* __restrict__ si, unsigned* __restrict__ neg)
{
    int row = blockIdx.x * 64 + (threadIdx.x >> 2);   // 128 blocks x 64 rows
    int cq  = threadIdx.x & 3;
    const ushort* r = (const ushort*)embr + (size_t)row * Cc + cq * 64;
    float s = 0.f;
    #pragma unroll
    for (int i = 0; i < 8; ++i) {
        bf16x8 v = *(const bf16x8*)(r + i * 8);
        #pragma unroll
        for (int j = 0; j < 8; ++j) {
            float f = __uint_as_float(((unsigned)(ushort)v[j]) << 16);
            s += f * f;
        }
    }
    s += __shfl_xor(s, 1);
    s += __shfl_xor(s, 2);
    if (cq == 0) {
        float sc = 10.0f / fmaxf(sqrtf(s), 1e-12f);
        scl[row] = sc;
        si[row]  = sc * sc * s;
        neg[row] = __float_as_uint(BIGF);
    }
}

// ---------------------------------------------------------------------------
// Kernel 2: Gram via bf16 MFMA on the RAW embeddings + fused masked-min.
// Scale folded into epilogue: d2 = si_i + si_j - 2*scl_i*scl_j*Graw.
// d2 clamped >= 0 BEFORE the uint-bit atomicMin (duplicate pairs = signal).
// ---------------------------------------------------------------------------
#define TILE 128
__global__ __launch_bounds__(256) void gram_mfma_min(
    const __hip_bfloat16* __restrict__ emb, const float* __restrict__ scl,
    const float* __restrict__ si, const int* __restrict__ mask,
    unsigned* __restrict__ neg)
{
    int b  = blockIdx.z;
    int i0 = blockIdx.y * TILE;
    int j0 = blockIdx.x * TILE;
    int w  = threadIdx.x >> 6, l = threadIdx.x & 63;
    int wr = w >> 1, wc = w & 1;          // wave's 64x64 quadrant
    int lr = l & 15, lg = l >> 4;         // lane row / k-group

    const short* E = (const short*)emb + (size_t)b * Kk * Cc;
    int arow = i0 + wr * 64 + lr;
    int brow = j0 + wc * 64 + lr;

    f32x4 acc[4][4] = {};
    for (int k0 = 0; k0 < Cc; k0 += 32) {
        bf16x8 af[4], bfr[4];
        #pragma unroll
        for (int f = 0; f < 4; ++f) {
            af[f]  = *(const bf16x8*)(E + (size_t)(arow + f*16) * Cc + k0 + lg*8);
            bfr[f] = *(const bf16x8*)(E + (size_t)(brow + f*16) * Cc + k0 + lg*8);
        }
        #pragma unroll
        for (int fi = 0; fi < 4; ++fi)
            #pragma unroll
            for (int fj = 0; fj < 4; ++fj)
                acc[fi][fj] = __builtin_amdgcn_mfma_f32_16x16x32_bf16(
                                  af[fi], bfr[fj], acc[fi][fj], 0, 0, 0);
    }

    const int* mb = mask + b * Kk;
    float sjv[4], cjv[4]; int jgv[4]; bool jva[4];
    #pragma unroll
    for (int fj = 0; fj < 4; ++fj) {
        int jg = j0 + wc*64 + fj*16 + lr;
        jgv[fj] = jg;
        sjv[fj] = si[b * Kk + jg];
        cjv[fj] = scl[b * Kk + jg];
        jva[fj] = (mb[jg] != 0);
    }
    #pragma unroll
    for (int fi = 0; fi < 4; ++fi) {
        #pragma unroll
        for (int r = 0; r < 4; ++r) {
            int ig = i0 + wr*64 + fi*16 + 4*lg + r;
            float siv = si[b * Kk + ig];
            float ci  = scl[b * Kk + ig];
            float m = BIGF;
            #pragma unroll
            for (int fj = 0; fj < 4; ++fj) {
                float d2 = fmaxf(siv + sjv[fj] - 2.0f * ci * cjv[fj] * acc[fi][fj][r], 0.0f);
                bool ok = jva[fj] && (jgv[fj] != ig);
                m = ok ? fminf(m, d2) : m;
            }
            #pragma unroll
            for (int off = 1; off < 16; off <<= 1)
                m = fminf(m, __shfl_xor(m, off));
            if (lr == 0)
                atomicMin(&neg[b * Kk + ig], __float_as_uint(m));
        }
    }
}

// ---------------------------------------------------------------------------
// Kernel 3: hinge = max(margin - sqrt(min_d2), 0) over valid anchors; mean.
// ---------------------------------------------------------------------------
__global__ __launch_bounds__(1024) void hinge_final(
    const unsigned* __restrict__ neg, const int* __restrict__ mask,
    float* __restrict__ out)
{
    float h = 0.f, v = 0.f;
    for (int i = threadIdx.x; i < BK; i += 1024) {
        if (mask[i] != 0) {
            float d = sqrtf(__uint_as_float(neg[i]));
            h += fmaxf(MARGIN_F - d, 0.f);
            v += 1.f;
        }
    }
    #pragma unroll
    for (int off = 32; off; off >>= 1) {
        h += __shfl_xor(h, off);
        v += __shfl_xor(v, off);
    }
    __shared__ float sh[16], sv[16];
    int w = threadIdx.x >> 6;
    if ((threadIdx.x & 63) == 0) { sh[w] = h; sv[w] = v; }
    __syncthreads();
    if (threadIdx.x == 0) {
        float H = 0.f, V = 0.f;
        #pragma unroll
        for (int i = 0; i < 16; ++i) { H += sh[i]; V += sv[i]; }
        out[0] = H / V;
    }
}

// ---------------------------------------------------------------------------
extern "C" void kernel_launch(void* const* d_in, const int* in_sizes, int n_in,
                              void* d_out, int out_size, void* d_ws, size_t ws_size,
                              hipStream_t stream) {
    const float* x     = (const float*)d_in[0];   // [B,C,H,W] fp32
    const int*   ind   = (const int*)d_in[1];     // [B,K] int32
    const int*   mask  = (const int*)d_in[2];     // [B,K] int32
    float* out = (float*)d_out;

    // ws layout: embr bf16 [B*K][C] (4 MB) | scl f32 [B*K] | si f32 [B*K]
    //            | neg u32 [B*K]
    __hip_bfloat16* embr = (__hip_bfloat16*)d_ws;
    float*    scl = (float*)((char*)d_ws + (size_t)BK * Cc * sizeof(__hip_bfloat16));
    float*    si  = scl + BK;
    unsigned* neg = (unsigned*)(si + BK);

    dim3 g0(32, Cc / 32, Bz);                 // (slice, c-group, batch)
    plane_gather<<<g0, 256, 0, stream>>>(x, ind, embr);
    rownorm<<<BK / 64, 256, 0, stream>>>(embr, scl, si, neg);
    dim3 g2(Kk / TILE, Kk / TILE, Bz);
    gram_mfma_min<<<g2, 256, 0, stream>>>(embr, scl, si, mask, neg);
    hinge_final<<<1, 1024, 0, stream>>>(neg, mask, out);
}

// Round 6
// 64.208 us; speedup vs baseline: 1.2315x; 1.1343x over previous
//
#include <hip/hip_runtime.h>
#include <hip/hip_bf16.h>

// Problem constants (fixed by the reference)
#define Bz 8
#define Cc 256
#define HWp 23104            // 152*152 = 32 slices * 722
#define SL  722              // positions per slice
#define Kk 1024
#define BK (Bz*Kk)
#define MARGIN_F 10.0f
#define BIGF 1e30f

typedef __attribute__((ext_vector_type(8))) short bf16x8;  // 8 bf16 = 4 VGPRs
typedef __attribute__((ext_vector_type(4))) float f32x4;   // MFMA 16x16 accumulator

// ---------------------------------------------------------------------------
// Kernel 0: plane-gather (unchanged from R4 — kept byte-identical so the
// total-time delta isolates the gram change).
// ---------------------------------------------------------------------------
__global__ __launch_bounds__(256) void plane_gather(
    const float* __restrict__ x, const int* __restrict__ ind,
    __hip_bfloat16* __restrict__ embr)
{
    __shared__ ushort pl[SL * 33];                 // 47652 B -> 3 blocks/CU
    int s  = blockIdx.x;                           // slice 0..31
    int c0 = blockIdx.y * 32;                      // channel group
    int b  = blockIdx.z;
    int lane = threadIdx.x & 63, w = threadIdx.x >> 6;
    int lo = s * SL;

    #pragma unroll
    for (int i = 0; i < 8; ++i) {
        int cl = w * 8 + i;
        const float2* src = (const float2*)(x + (size_t)(b * Cc + c0 + cl) * HWp + lo);
        #pragma unroll
        for (int it = 0; it < 6; ++it) {
            int idx2 = it * 64 + lane;
            if (idx2 < SL / 2) {
                float2 v = src[idx2];
                pl[(idx2 * 2 + 0) * 33 + cl] = __hip_bfloat16_raw(__float2bfloat16(v.x)).x;
                pl[(idx2 * 2 + 1) * 33 + cl] = __hip_bfloat16_raw(__float2bfloat16(v.y)).x;
            }
        }
    }
    __syncthreads();

    const int* indb = ind + b * Kk;
    #pragma unroll
    for (int kk = 0; kk < 4; ++kk) {
        int k = kk * 256 + threadIdx.x;
        unsigned off = (unsigned)(indb[k] - lo);
        if (off < (unsigned)SL) {
            const ushort* row = &pl[off * 33];
            uint dw[16];
            #pragma unroll
            for (int c2 = 0; c2 < 16; ++c2)
                dw[c2] = (uint)row[2 * c2] | ((uint)row[2 * c2 + 1] << 16);
            uint4* dst = (uint4*)((ushort*)embr + (size_t)(b * Kk + k) * Cc + c0);
            dst[0] = make_uint4(dw[0],  dw[1],  dw[2],  dw[3]);
            dst[1] = make_uint4(dw[4],  dw[5],  dw[6],  dw[7]);
            dst[2] = make_uint4(dw[8],  dw[9],  dw[10], dw[11]);
            dst[3] = make_uint4(dw[12], dw[13], dw[14], dw[15]);
        }
    }
}

// ---------------------------------------------------------------------------
// Kernel 1: rownorm (unchanged).
// ---------------------------------------------------------------------------
__global__ __launch_bounds__(256) void rownorm(
    const __hip_bfloat16* __restrict__ embr, float* __restrict__ scl,
    float* __restrict__ si, unsigned* __restrict__ neg)
{
    int row = blockIdx.x * 64 + (threadIdx.x >> 2);   // 128 blocks x 64 rows
    int cq  = threadIdx.x & 3;
    const ushort* r = (const ushort*)embr + (size_t)row * Cc + cq * 64;
    float s = 0.f;
    #pragma unroll
    for (int i = 0; i < 8; ++i) {
        bf16x8 v = *(const bf16x8*)(r + i * 8);
        #pragma unroll
        for (int j = 0; j < 8; ++j) {
            float f = __uint_as_float(((unsigned)(ushort)v[j]) << 16);
            s += f * f;
        }
    }
    s += __shfl_xor(s, 1);
    s += __shfl_xor(s, 2);
    if (cq == 0) {
        float sc = 10.0f / fmaxf(sqrtf(s), 1e-12f);
        scl[row] = sc;
        si[row]  = sc * sc * s;
        neg[row] = __float_as_uint(BIGF);
    }
}

// ---------------------------------------------------------------------------
// Kernel 2: Gram via bf16 MFMA, now with LDS-staged panels.
// R4 lesson: no-LDS fragment loads were 16B/lane at 512B stride = 64 distinct
// 64B lines per instruction -> ~536 MB scattered L2 traffic + TA-issue bound.
// Now: per 64-k step, stage A[128][64] + B[128][64] bf16 (16KB+16KB) via
// global_load_lds width=16 (wave writes 1024B linear LDS; per-lane global
// source PRE-SWIZZLED so that LDS[row][slot] holds k-chunk slot^(row&7);
// ds_read_b128 applies the same XOR -> 2-way conflicts only = free).
// K accumulation order (k=0..255 in 32-steps) identical to R4 -> bitwise-
// identical results.  Epilogue unchanged: d2 = si_i+si_j-2*scl_i*scl_j*G,
// clamped >=0 BEFORE the uint-bit atomicMin (duplicate pairs = the signal).
// ---------------------------------------------------------------------------
#define TILE 128
__global__ __launch_bounds__(256) void gram_mfma_min(
    const __hip_bfloat16* __restrict__ emb, const float* __restrict__ scl,
    const float* __restrict__ si, const int* __restrict__ mask,
    unsigned* __restrict__ neg)
{
    __shared__ __align__(16) short As[TILE * 64];   // 16 KB, row-major [128][64]
    __shared__ __align__(16) short Bs[TILE * 64];   // 16 KB
    int b  = blockIdx.z;
    int i0 = blockIdx.y * TILE;
    int j0 = blockIdx.x * TILE;
    int w  = threadIdx.x >> 6, l = threadIdx.x & 63;
    int wr = w >> 1, wc = w & 1;          // wave's 64x64 quadrant
    int lr = l & 15, lg = l >> 4;         // lane row / k-group (for MFMA frags)

    const short* E  = (const short*)emb + (size_t)b * Kk * Cc;
    const short* EA = E + (size_t)i0 * Cc;
    const short* EB = E + (size_t)j0 * Cc;

    // staging decomposition: instruction t (=w*4+q) fills LDS rows t*8..t*8+7;
    // lane l -> row offset l/8, slot l%8; source k-chunk = (l%8) ^ (l/8).
    int lrow = l >> 3;
    int lsub = (l & 7) ^ lrow;

    f32x4 acc[4][4] = {};
    for (int k0 = 0; k0 < Cc; k0 += 64) {
        #pragma unroll
        for (int q = 0; q < 4; ++q) {
            int t = w * 4 + q;
            int r = t * 8 + lrow;
            __builtin_amdgcn_global_load_lds(
                (const __attribute__((address_space(1))) void*)(EA + (size_t)r * Cc + k0 + lsub * 8),
                (__attribute__((address_space(3))) void*)&As[t * 512], 16, 0, 0);
            __builtin_amdgcn_global_load_lds(
                (const __attribute__((address_space(1))) void*)(EB + (size_t)r * Cc + k0 + lsub * 8),
                (__attribute__((address_space(3))) void*)&Bs[t * 512], 16, 0, 0);
        }
        __syncthreads();   // compiler drains vmcnt before s_barrier (m97 pattern)

        #pragma unroll
        for (int kk = 0; kk < 2; ++kk) {
            bf16x8 af[4], bf[4];
            #pragma unroll
            for (int f = 0; f < 4; ++f) {
                int ra = wr * 64 + f * 16 + lr;
                af[f] = *(const bf16x8*)&As[ra * 64 + (((kk * 4 + lg) ^ (ra & 7)) << 3)];
                int rb = wc * 64 + f * 16 + lr;
                bf[f] = *(const bf16x8*)&Bs[rb * 64 + (((kk * 4 + lg) ^ (rb & 7)) << 3)];
            }
            #pragma unroll
            for (int fi = 0; fi < 4; ++fi)
                #pragma unroll
                for (int fj = 0; fj < 4; ++fj)
                    acc[fi][fj] = __builtin_amdgcn_mfma_f32_16x16x32_bf16(
                                      af[fi], bf[fj], acc[fi][fj], 0, 0, 0);
        }
        __syncthreads();
    }

    const int* mb = mask + b * Kk;
    float sjv[4], cjv[4]; int jgv[4]; bool jva[4];
    #pragma unroll
    for (int fj = 0; fj < 4; ++fj) {
        int jg = j0 + wc*64 + fj*16 + lr;
        jgv[fj] = jg;
        sjv[fj] = si[b * Kk + jg];
        cjv[fj] = scl[b * Kk + jg];
        jva[fj] = (mb[jg] != 0);
    }
    #pragma unroll
    for (int fi = 0; fi < 4; ++fi) {
        #pragma unroll
        for (int r = 0; r < 4; ++r) {
            int ig = i0 + wr*64 + fi*16 + 4*lg + r;
            float siv = si[b * Kk + ig];
            float ci  = scl[b * Kk + ig];
            float m = BIGF;
            #pragma unroll
            for (int fj = 0; fj < 4; ++fj) {
                float d2 = fmaxf(siv + sjv[fj] - 2.0f * ci * cjv[fj] * acc[fi][fj][r], 0.0f);
                bool ok = jva[fj] && (jgv[fj] != ig);
                m = ok ? fminf(m, d2) : m;
            }
            #pragma unroll
            for (int off = 1; off < 16; off <<= 1)
                m = fminf(m, __shfl_xor(m, off));
            if (lr == 0)
                atomicMin(&neg[b * Kk + ig], __float_as_uint(m));
        }
    }
}

// ---------------------------------------------------------------------------
// Kernel 3: hinge + mean (unchanged).
// ---------------------------------------------------------------------------
__global__ __launch_bounds__(1024) void hinge_final(
    const unsigned* __restrict__ neg, const int* __restrict__ mask,
    float* __restrict__ out)
{
    float h = 0.f, v = 0.f;
    for (int i = threadIdx.x; i < BK; i += 1024) {
        if (mask[i] != 0) {
            float d = sqrtf(__uint_as_float(neg[i]));
            h += fmaxf(MARGIN_F - d, 0.f);
            v += 1.f;
        }
    }
    #pragma unroll
    for (int off = 32; off; off >>= 1) {
        h += __shfl_xor(h, off);
        v += __shfl_xor(v, off);
    }
    __shared__ float sh[16], sv[16];
    int w = threadIdx.x >> 6;
    if ((threadIdx.x & 63) == 0) { sh[w] = h; sv[w] = v; }
    __syncthreads();
    if (threadIdx.x == 0) {
        float H = 0.f, V = 0.f;
        #pragma unroll
        for (int i = 0; i < 16; ++i) { H += sh[i]; V += sv[i]; }
        out[0] = H / V;
    }
}

// ---------------------------------------------------------------------------
extern "C" void kernel_launch(void* const* d_in, const int* in_sizes, int n_in,
                              void* d_out, int out_size, void* d_ws, size_t ws_size,
                              hipStream_t stream) {
    const float* x     = (const float*)d_in[0];   // [B,C,H,W] fp32
    const int*   ind   = (const int*)d_in[1];     // [B,K] int32
    const int*   mask  = (const int*)d_in[2];     // [B,K] int32
    float* out = (float*)d_out;

    // ws layout: embr bf16 [B*K][C] (4 MB) | scl f32 [B*K] | si f32 [B*K]
    //            | neg u32 [B*K]
    __hip_bfloat16* embr = (__hip_bfloat16*)d_ws;
    float*    scl = (float*)((char*)d_ws + (size_t)BK * Cc * sizeof(__hip_bfloat16));
    float*    si  = scl + BK;
    unsigned* neg = (unsigned*)(si + BK);

    dim3 g0(32, Cc / 32, Bz);                 // (slice, c-group, batch)
    plane_gather<<<g0, 256, 0, stream>>>(x, ind, embr);
    rownorm<<<BK / 64, 256, 0, stream>>>(embr, scl, si, neg);
    dim3 g2(Kk / TILE, Kk / TILE, Bz);
    gram_mfma_min<<<g2, 256, 0, stream>>>(embr, scl, si, mask, neg);
    hinge_final<<<1, 1024, 0, stream>>>(neg, mask, out);
}

// Round 7
// 63.278 us; speedup vs baseline: 1.2496x; 1.0147x over previous
//
#include <hip/hip_runtime.h>
#include <hip/hip_bf16.h>

// Problem constants (fixed by the reference)
#define Bz 8
#define Cc 256
#define HWp 23104            // 152*152 = 76 slices * 304
#define SLC 304              // positions per slice (304*4B = 1216B = 19 lines, 64B-aligned starts)
#define Kk 1024
#define BK (Bz*Kk)
#define MARGIN_F 10.0f
#define BIGF 1e30f

typedef __attribute__((ext_vector_type(8))) short bf16x8;  // 8 bf16 = 4 VGPRs
typedef __attribute__((ext_vector_type(4))) float f32x4;   // MFMA 16x16 accumulator

__device__ __forceinline__ uint pk2(float a, float b) {
    return (uint)__hip_bfloat16_raw(__float2bfloat16(a)).x
         | ((uint)__hip_bfloat16_raw(__float2bfloat16(b)).x << 16);
}

// ---------------------------------------------------------------------------
// Kernel 0: plane-gather, DMA-style.
// R4/R5 lesson (Little's law): the reg-staged stream kept only ~6 loads
// (3 KB) in flight/wave -> ~36 KB/CU < 24.6 GB/s x ~1.8us latency product ->
// latency-throttled at ~3.8 TB/s.  Fix: global_load_lds width=16 (no VGPR
// data round-trip, deep vmcnt queue): 4 blocks/CU x 4 waves x ~9KB issued
// = ~150 KB in flight/CU.  Block = 32 channels x 304-position slice:
//   reads : fp32 slice rows, 64B-aligned, wave-linear LDS dest (rule #21:
//           both sides linear), 189 MB total = the input, read once
//   gather: ~13.5 in-range k per block; convert bf16 + pack in registers
//   writes: per k ONE full 64B line embr[k][c0..c0+31], written exactly once
// ---------------------------------------------------------------------------
__global__ __launch_bounds__(256) void plane_gather(
    const float* __restrict__ x, const int* __restrict__ ind,
    __hip_bfloat16* __restrict__ embr)
{
    __shared__ float pl[32 * SLC];                 // 38912 B -> 4 blocks/CU
    int s  = blockIdx.x;                           // slice 0..75
    int c0 = blockIdx.y * 32;                      // channel group
    int b  = blockIdx.z;
    int lane = threadIdx.x & 63, w = threadIdx.x >> 6;
    int lo = s * SLC;

    // wave w streams rows w*8..w*8+7; per row: 64-lane issue + 12-lane issue
    #pragma unroll
    for (int rr = 0; rr < 8; ++rr) {
        int row = w * 8 + rr;
        const float* src = x + (size_t)(b * Cc + c0 + row) * HWp + lo;
        __builtin_amdgcn_global_load_lds(
            (const __attribute__((address_space(1))) void*)(src + lane * 4),
            (__attribute__((address_space(3))) void*)&pl[row * SLC], 16, 0, 0);
        if (lane < 12)
            __builtin_amdgcn_global_load_lds(
                (const __attribute__((address_space(1))) void*)(src + 256 + lane * 4),
                (__attribute__((address_space(3))) void*)&pl[row * SLC + 256], 16, 0, 0);
    }
    __syncthreads();   // drains vmcnt (compiler-inserted) before gather

    const int* indb = ind + b * Kk;
    #pragma unroll
    for (int kk = 0; kk < 4; ++kk) {
        int k = kk * 256 + threadIdx.x;
        unsigned off = (unsigned)(indb[k] - lo);
        if (off < (unsigned)SLC) {
            ushort* dst = (ushort*)embr + (size_t)(b * Kk + k) * Cc + c0;
            #pragma unroll
            for (int g = 0; g < 4; ++g) {
                uint4 o;
                o.x = pk2(pl[(g*8+0)*SLC + off], pl[(g*8+1)*SLC + off]);
                o.y = pk2(pl[(g*8+2)*SLC + off], pl[(g*8+3)*SLC + off]);
                o.z = pk2(pl[(g*8+4)*SLC + off], pl[(g*8+5)*SLC + off]);
                o.w = pk2(pl[(g*8+6)*SLC + off], pl[(g*8+7)*SLC + off]);
                ((uint4*)dst)[g] = o;
            }
        }
    }
}

// ---------------------------------------------------------------------------
// Kernel 1: rownorm — ONE WAVE per row (old version ran at 2 waves/CU).
// Wave reads its 512B row coalesced (uint2/lane = 4 bf16), shfl-reduces ssq,
// writes scl = 10/max(sqrt(ssq),eps) and initializes neg_min.
// (si is NOT stored: ||scl*row||^2 == 100 by construction.)
// ---------------------------------------------------------------------------
__global__ __launch_bounds__(256) void rownorm(
    const __hip_bfloat16* __restrict__ embr, float* __restrict__ scl,
    unsigned* __restrict__ neg)
{
    int row  = blockIdx.x * 4 + (threadIdx.x >> 6);
    int lane = threadIdx.x & 63;
    uint2 v = *((const uint2*)((const ushort*)embr + (size_t)row * Cc) + lane);
    float f0 = __uint_as_float(v.x << 16);
    float f1 = __uint_as_float(v.x & 0xffff0000u);
    float f2 = __uint_as_float(v.y << 16);
    float f3 = __uint_as_float(v.y & 0xffff0000u);
    float s = f0*f0 + f1*f1 + f2*f2 + f3*f3;
    #pragma unroll
    for (int off = 32; off; off >>= 1) s += __shfl_xor(s, off);
    if (lane == 0) {
        scl[row] = 10.0f / fmaxf(sqrtf(s), 1e-12f);
        neg[row] = __float_as_uint(BIGF);
    }
}

// ---------------------------------------------------------------------------
// Kernel 2: Gram via bf16 MFMA with LDS-staged panels (unchanged from R5,
// which was the verified 8.6us win) + fused masked-min.  Epilogue now uses
// d2 = 200 - 2*scl_i*scl_j*Graw  (si == sj == 100 identically), clamped >=0
// BEFORE the uint-bit atomicMin (duplicate pairs = the loss signal).
// ---------------------------------------------------------------------------
#define TILE 128
__global__ __launch_bounds__(256) void gram_mfma_min(
    const __hip_bfloat16* __restrict__ emb, const float* __restrict__ scl,
    const int* __restrict__ mask, unsigned* __restrict__ neg)
{
    __shared__ __align__(16) short As[TILE * 64];   // 16 KB, row-major [128][64]
    __shared__ __align__(16) short Bs[TILE * 64];   // 16 KB
    int b  = blockIdx.z;
    int i0 = blockIdx.y * TILE;
    int j0 = blockIdx.x * TILE;
    int w  = threadIdx.x >> 6, l = threadIdx.x & 63;
    int wr = w >> 1, wc = w & 1;          // wave's 64x64 quadrant
    int lr = l & 15, lg = l >> 4;         // lane row / k-group (for MFMA frags)

    const short* E  = (const short*)emb + (size_t)b * Kk * Cc;
    const short* EA = E + (size_t)i0 * Cc;
    const short* EB = E + (size_t)j0 * Cc;

    // staging: instruction t (=w*4+q) fills LDS rows t*8..t*8+7;
    // lane l -> row offset l/8, slot l%8; source k-chunk = (l%8) ^ (l/8).
    int lrow = l >> 3;
    int lsub = (l & 7) ^ lrow;

    f32x4 acc[4][4] = {};
    for (int k0 = 0; k0 < Cc; k0 += 64) {
        #pragma unroll
        for (int q = 0; q < 4; ++q) {
            int t = w * 4 + q;
            int r = t * 8 + lrow;
            __builtin_amdgcn_global_load_lds(
                (const __attribute__((address_space(1))) void*)(EA + (size_t)r * Cc + k0 + lsub * 8),
                (__attribute__((address_space(3))) void*)&As[t * 512], 16, 0, 0);
            __builtin_amdgcn_global_load_lds(
                (const __attribute__((address_space(1))) void*)(EB + (size_t)r * Cc + k0 + lsub * 8),
                (__attribute__((address_space(3))) void*)&Bs[t * 512], 16, 0, 0);
        }
        __syncthreads();

        #pragma unroll
        for (int kk = 0; kk < 2; ++kk) {
            bf16x8 af[4], bf[4];
            #pragma unroll
            for (int f = 0; f < 4; ++f) {
                int ra = wr * 64 + f * 16 + lr;
                af[f] = *(const bf16x8*)&As[ra * 64 + (((kk * 4 + lg) ^ (ra & 7)) << 3)];
                int rb = wc * 64 + f * 16 + lr;
                bf[f] = *(const bf16x8*)&Bs[rb * 64 + (((kk * 4 + lg) ^ (rb & 7)) << 3)];
            }
            #pragma unroll
            for (int fi = 0; fi < 4; ++fi)
                #pragma unroll
                for (int fj = 0; fj < 4; ++fj)
                    acc[fi][fj] = __builtin_amdgcn_mfma_f32_16x16x32_bf16(
                                      af[fi], bf[fj], acc[fi][fj], 0, 0, 0);
        }
        __syncthreads();
    }

    const int* mb = mask + b * Kk;
    float cjv[4]; int jgv[4]; bool jva[4];
    #pragma unroll
    for (int fj = 0; fj < 4; ++fj) {
        int jg = j0 + wc*64 + fj*16 + lr;
        jgv[fj] = jg;
        cjv[fj] = scl[b * Kk + jg];
        jva[fj] = (mb[jg] != 0);
    }
    #pragma unroll
    for (int fi = 0; fi < 4; ++fi) {
        #pragma unroll
        for (int r = 0; r < 4; ++r) {
            int ig = i0 + wr*64 + fi*16 + 4*lg + r;
            float ci = scl[b * Kk + ig];
            float m = BIGF;
            #pragma unroll
            for (int fj = 0; fj < 4; ++fj) {
                float d2 = fmaxf(200.0f - 2.0f * ci * cjv[fj] * acc[fi][fj][r], 0.0f);
                bool ok = jva[fj] && (jgv[fj] != ig);
                m = ok ? fminf(m, d2) : m;
            }
            #pragma unroll
            for (int off = 1; off < 16; off <<= 1)
                m = fminf(m, __shfl_xor(m, off));
            if (lr == 0)
                atomicMin(&neg[b * Kk + ig], __float_as_uint(m));
        }
    }
}

// ---------------------------------------------------------------------------
// Kernel 3: hinge = max(margin - sqrt(min_d2), 0) over valid anchors; mean.
// ---------------------------------------------------------------------------
__global__ __launch_bounds__(1024) void hinge_final(
    const unsigned* __restrict__ neg, const int* __restrict__ mask,
    float* __restrict__ out)
{
    float h = 0.f, v = 0.f;
    for (int i = threadIdx.x; i < BK; i += 1024) {
        if (mask[i] != 0) {
            float d = sqrtf(__uint_as_float(neg[i]));
            h += fmaxf(MARGIN_F - d, 0.f);
            v += 1.f;
        }
    }
    #pragma unroll
    for (int off = 32; off; off >>= 1) {
        h += __shfl_xor(h, off);
        v += __shfl_xor(v, off);
    }
    __shared__ float sh[16], sv[16];
    int w = threadIdx.x >> 6;
    if ((threadIdx.x & 63) == 0) { sh[w] = h; sv[w] = v; }
    __syncthreads();
    if (threadIdx.x == 0) {
        float H = 0.f, V = 0.f;
        #pragma unroll
        for (int i = 0; i < 16; ++i) { H += sh[i]; V += sv[i]; }
        out[0] = H / V;
    }
}

// ---------------------------------------------------------------------------
extern "C" void kernel_launch(void* const* d_in, const int* in_sizes, int n_in,
                              void* d_out, int out_size, void* d_ws, size_t ws_size,
                              hipStream_t stream) {
    const float* x     = (const float*)d_in[0];   // [B,C,H,W] fp32
    const int*   ind   = (const int*)d_in[1];     // [B,K] int32
    const int*   mask  = (const int*)d_in[2];     // [B,K] int32
    float* out = (float*)d_out;

    // ws layout: embr bf16 [B*K][C] (4 MB) | scl f32 [B*K] | neg u32 [B*K]
    __hip_bfloat16* embr = (__hip_bfloat16*)d_ws;
    float*    scl = (float*)((char*)d_ws + (size_t)BK * Cc * sizeof(__hip_bfloat16));
    unsigned* neg = (unsigned*)(scl + BK);

    dim3 g0(HWp / SLC, Cc / 32, Bz);          // (76 slices, 8 c-groups, 8 b)
    plane_gather<<<g0, 256, 0, stream>>>(x, ind, embr);
    rownorm<<<BK / 4, 256, 0, stream>>>(embr, scl, neg);
    dim3 g2(Kk / TILE, Kk / TILE, Bz);
    gram_mfma_min<<<g2, 256, 0, stream>>>(embr, scl, mask, neg);
    hinge_final<<<1, 1024, 0, stream>>>(neg, mask, out);
}